// Round 6
// baseline (1187.498 us; speedup 1.0000x reference)
//
#include <hip/hip_runtime.h>
#include <stdint.h>

// ---------------------------------------------------------------------------
// FixedPointLSTM (B=64, T=256, I=512, H=1024), fixed-point Q8.8 with hard
// activations. All fxp grid values are exactly representable in fp16; fp16
// MFMA with fp32 accumulate matches the numpy reference to ~1 grid step.
//
// R16: dual-group interleave (structural). Ledger: R11 FAIL, R12 -30us,
// R13 -7us (kept), R14 -315us, R15 neutral -> placement/transaction tweaks
// on the single-stream skeleton are exhausted; 65% of the step is exposed
// cross-block round-trip latency.
// New decomposition: 4 communities x 64 ranks (= 256 blocks, 1/CU pinned).
// Block (p, rank): cols j0=16*rank..+15, FOUR gates (wave w owns gate w ->
// B-frags 32 x h8 = 128 VGPR), serving TWO batch octets gA=2p, gB=2p+1.
// Each iteration runs phase A then phase B; each phase is the proven R13
// protocol (w0 poll -> bar -> stage -> bar -> MFMA -> gates -> drain bar ->
// flag -> out). Group A's flag propagates during phase B (and vice versa),
// hiding the h->flag->poll->load round trip under real work.
// Gates: per-cell ownership. Wave w computes g_w = fxp(gx + fxp(acc+bhh))
// for its gate, writes LDS xch[cell][4]; waves 2-3 then each own one
// (row,col) cell: read 4 gates (b64), activations, c/h update, publish.
// gx repacked [t][grp][rank][w][col 16][row 8] fp16 (gemm keeps h4 stores).
// Per-gate K-accumulation order (even/odd chains) is unchanged -> bitwise
// identical gh. Flags: [8 grp][64 rank] u32 (2 KB, memset already covers).
// ---------------------------------------------------------------------------

typedef _Float16 h8 __attribute__((ext_vector_type(8)));
typedef _Float16 h4 __attribute__((ext_vector_type(4)));
typedef float f4 __attribute__((ext_vector_type(4)));
typedef unsigned long long u64;

#define MFMA16(a, b, c) __builtin_amdgcn_mfma_f32_16x16x32_f16(a, b, c, 0, 0, 0)

__device__ __forceinline__ float fxp(float x) {
  float q = rintf(x * 256.0f) * 0.00390625f;
  return fminf(fmaxf(q, -128.0f), 127.99609375f);
}

// round-only: for values provably in [-128, 127.996] the clamp is a no-op.
__device__ __forceinline__ float fxp_rnd(float x) {
  return rintf(x * 256.0f) * 0.00390625f;
}

__device__ __forceinline__ float hsig(float x) {
  return fminf(fmaxf(x / 6.0f + 0.5f, 0.0f), 1.0f);  // IEEE div to match np
}

// ---- quantize fp32 -> fxp grid, store fp16 ---------------------------------
__global__ void qf16_kernel(const float* __restrict__ in,
                            _Float16* __restrict__ out, int n4) {
  int i = blockIdx.x * 256 + threadIdx.x;
  if (i < n4) {
    float4 v = ((const float4*)in)[i];
    h4 o;
    o[0] = (_Float16)fxp(v.x); o[1] = (_Float16)fxp(v.y);
    o[2] = (_Float16)fxp(v.z); o[3] = (_Float16)fxp(v.w);
    ((h4*)out)[i] = o;
  }
}

// quantize + transpose x: in [64][256][512] -> rows m = t*64+b, [16384][512]
__global__ void qx_kernel(const float* __restrict__ in,
                          _Float16* __restrict__ out) {
  int i4 = blockIdx.x * 256 + threadIdx.x;  // over 16384*128 float4s
  int col4 = i4 & 127;
  int row = i4 >> 7;  // b*256 + t
  int b = row >> 8, tt = row & 255;
  float4 v = ((const float4*)in)[i4];
  h4 o;
  o[0] = (_Float16)fxp(v.x); o[1] = (_Float16)fxp(v.y);
  o[2] = (_Float16)fxp(v.z); o[3] = (_Float16)fxp(v.w);
  ((h4*)out)[(size_t)((tt << 6) + b) * 128 + col4] = o;
}

__global__ void qf32_kernel(const float* __restrict__ in,
                            float* __restrict__ out, int n4) {
  int i = blockIdx.x * 256 + threadIdx.x;
  if (i < n4) {
    float4 v = ((const float4*)in)[i];
    float4 o;
    o.x = fxp(v.x); o.y = fxp(v.y); o.z = fxp(v.z); o.w = fxp(v.w);
    ((float4*)out)[i] = o;
  }
}

// h0 -> hbuf buffer 0, layout [grp=8][buf=2][row=8][1024] fp16
__global__ void qh0_kernel(const float* __restrict__ in,
                           _Float16* __restrict__ hbuf) {
  int i = blockIdx.x * 256 + threadIdx.x;  // over 64*1024/4
  int col4 = i & 255, b = i >> 8;
  float4 v = ((const float4*)in)[i];
  h4 o;
  o[0] = (_Float16)fxp(v.x); o[1] = (_Float16)fxp(v.y);
  o[2] = (_Float16)fxp(v.z); o[3] = (_Float16)fxp(v.w);
  *(h4*)(hbuf + (size_t)(b >> 3) * 16384 + (b & 7) * 1024 + col4 * 4) = o;
}

// ---- async global->LDS helper (width 16B; LDS dest = wave-uniform base) ----
__device__ __forceinline__ void gload_lds16(const _Float16* g, _Float16* l) {
  __builtin_amdgcn_global_load_lds(
      (const __attribute__((address_space(1))) uint32_t*)g,
      (__attribute__((address_space(3))) uint32_t*)l, 16, 0, 0);
}

// ---------------------------------------------------------------------------
// gx = fxp(x_q @ w_ih_q^T + b_ih_q), packed:
//   [t 256][grp 8][rank 64][gate w 4][col 16][row 8] fp16 (128 MB total).
// Consumer wave w (q<2 lanes) h4-loads [w][cl][q*4..+3].
// ---------------------------------------------------------------------------
__global__ __launch_bounds__(256) void gemm_gx_kernel(
    const _Float16* __restrict__ Xq,   // [16384][512], m = t*64+b
    const _Float16* __restrict__ Wih,  // [4096][512]
    const float* __restrict__ bih,     // [4096]
    _Float16* __restrict__ gx)         // packed, see above
{
  __shared__ _Float16 As[128 * 32];
  __shared__ _Float16 Bs[128 * 32];
  const int tid = threadIdx.x;
  const int lane = tid & 63;
  const int w = tid >> 6;
  const int wm = (w >> 1) * 64;
  const int wn = (w & 1) * 64;
  const int m0 = blockIdx.x * 128;
  const int n0 = blockIdx.y * 128;
  const int cl = lane & 15, q = lane >> 4;

  f4 acc[4][4] = {};

  for (int k0 = 0; k0 < 512; k0 += 32) {
#pragma unroll
    for (int i = 0; i < 2; i++) {
      int idx = i * 256 + tid;
      int row = idx >> 2;
      int kc = (idx & 3) << 3;
      int wbase = (i * 256 + (tid & 192)) << 3;  // wave-uniform LDS base
      gload_lds16(Xq + (size_t)(m0 + row) * 512 + k0 + kc, As + wbase);
      gload_lds16(Wih + (size_t)(n0 + row) * 512 + k0 + kc, Bs + wbase);
    }
    __syncthreads();
    h8 af[4], bf[4];
#pragma unroll
    for (int mt = 0; mt < 4; mt++)
      af[mt] = *(const h8*)(As + (wm + mt * 16 + cl) * 32 + q * 8);
#pragma unroll
    for (int nt = 0; nt < 4; nt++)
      bf[nt] = *(const h8*)(Bs + (wn + nt * 16 + cl) * 32 + q * 8);
#pragma unroll
    for (int mt = 0; mt < 4; mt++)
#pragma unroll
      for (int nt = 0; nt < 4; nt++)
        acc[mt][nt] = MFMA16(af[mt], bf[nt], acc[mt][nt]);
    __syncthreads();
  }

#pragma unroll
  for (int nt = 0; nt < 4; nt++) {
    const int n = n0 + wn + nt * 16 + cl;  // gate-col 0..4095
    const float bv = bih[n];
    const int wg = n >> 10, c1024 = n & 1023;
    const int rk = c1024 >> 4, col = c1024 & 15;
#pragma unroll
    for (int mt = 0; mt < 4; mt++) {
      const int m = m0 + wm + mt * 16 + q * 4;  // 4-aligned
      const int b = m & 63, tt = m >> 6;
      const int grp = b >> 3, rb = b & 7;  // rb in {0,4}
      h4 pk;
#pragma unroll
      for (int r = 0; r < 4; r++) pk[r] = (_Float16)fxp(acc[mt][nt][r] + bv);
      *(h4*)(gx + ((((size_t)tt * 8 + grp) * 64 + rk) * 4 + wg) * 128 +
             col * 8 + rb) = pk;
    }
  }
}

// ---------------------------------------------------------------------------
// Persistent recurrence, dual-group. 256 blocks x 256 threads, a255 pin ->
// 1 block/CU (deterministic spread). Block = (p = blockIdx>>6, rank =
// blockIdx&63): cols 16*rank..+15 x 4 gates; groups gA=2p (phase A) and
// gB=2p+1 (phase B) per iteration. Communities of 64 blocks are closed.
// ---------------------------------------------------------------------------
__global__ __launch_bounds__(256, 1) void lstm_kernel(
    const _Float16* __restrict__ Whh,  // [4096][1024] quantized
    const float* __restrict__ bhh,     // [4096] quantized
    const _Float16* __restrict__ gx,   // packed [256][8][64][4][16][8]
    const float* __restrict__ c0,      // [64][1024]
    _Float16* __restrict__ hbuf,       // [8][2][8][1024] fp16
    float* __restrict__ out,           // [64][256][1024] ++ h_n ++ c_n
    unsigned* __restrict__ flags)      // [8][64]
{
  // Residency pin: force total regs/wave > 256 -> 1 wave/SIMD -> 1 block/CU.
  asm volatile("v_accvgpr_write_b32 a255, 0" ::: "a255");

  const int tid = threadIdx.x;
  const int lane = tid & 63;
  const int w = tid >> 6;
  const int cl = lane & 15, q = lane >> 4;

  const int p = blockIdx.x >> 6;
  const int rank = blockIdx.x & 63;
  const int gA = p << 1, gB = (p << 1) | 1;
  const int j0 = rank << 4;

  // persistent B fragments: wave w = gate w, 16 cols: 32 x h8 = 128 regs
  const int brow = (w << 10) + j0 + cl;
  h8 B[32];
#pragma unroll
  for (int kt = 0; kt < 32; kt++)
    B[kt] = *(const h8*)(Whh + (size_t)brow * 1024 + (kt << 5) + (q << 3));
  const float bh = bhh[brow];

  // cell ownership (gates phase): waves 2-3, one (row,col) cell each
  const int isCell = tid >= 128;
  const int cell = tid & 127;
  const int row_c = cell >> 4, col_c = cell & 15;
  const int jc = j0 + col_c;

  float cA = 0.f, cB = 0.f, hA = 0.f, hB = 0.f;
  if (isCell) {
    cA = c0[((gA << 3) + row_c) * 1024 + jc];
    cB = c0[((gB << 3) + row_c) * 1024 + jc];
  }

  // LDS: two h stages [8][1032] (pad: A-frag reads arow*1032 conflict-free,
  // verified R6) + two xch tiles [128 cells][4 gates] fp16.
  __shared__ alignas(16) _Float16 hsA[8 * 1032];
  __shared__ alignas(16) _Float16 hsB[8 * 1032];
  __shared__ alignas(16) _Float16 xchA[512];
  __shared__ alignas(16) _Float16 xchB[512];

  const int arow = lane & 7;
  const u64* hb64 = (const u64*)hbuf;  // per grp: 4096 u64 (2 bufs x 2048)
  // stage addressing (R13): thread (row=tid>>5, c=tid&31) loads u64 c+32j,
  // writes LDS row*1032 + 4c + 128j halves (4-way banks).
  const int srow = tid >> 5, sc = tid & 31;
  const size_t lsA = (size_t)gA * 4096 + (size_t)srow * 256 + sc;
  const size_t lsB = (size_t)gB * 4096 + (size_t)srow * 256 + sc;
  _Float16* ldA = hsA + srow * 1032 + (sc << 2);
  _Float16* ldB = hsB + srow * 1032 + (sc << 2);

  unsigned* flagA = flags + (gA << 6) + rank;
  unsigned* flagB = flags + (gB << 6) + rank;
  const u64* f2A = (const u64*)(flags + (gA << 6));  // 32 u64 per group
  const u64* f2B = (const u64*)(flags + (gB << 6));

  auto phase = [&](int G, const size_t lsrc, _Float16* ldst, _Float16* hsG,
                   _Float16* xchG, const u64* f2, unsigned* myflag, float& cG,
                   float& hG, int t) {
    // ---- w0 poll of the group's 64 flags (32 u64, lanes duplicated) ------
    if (t) {
      if (w == 0) {
        const unsigned tt = (unsigned)t;
        int it = 0;
        for (;;) {
          u64 v = __hip_atomic_load(&f2[lane & 31], __ATOMIC_RELAXED,
                                    __HIP_MEMORY_SCOPE_AGENT);
          bool ok = ((unsigned)v >= tt) && ((unsigned)(v >> 32) >= tt);
          if (__ballot(ok) == ~0ull) break;
          if (++it > (1 << 14)) break;  // hang insurance (loudly wrong)
          __builtin_amdgcn_s_sleep(1);
        }
      }
      __syncthreads();
    }

    // ---- gx fragment for this wave's gate: h4 [w][cl][q*4] (q<2) ---------
    h4 gxv = {};
    if (q < 2)
      gxv = *(const h4*)(gx + ((((size_t)t * 8 + G) * 64 + rank) * 4 + w) * 128 +
                         cl * 8 + (q << 2));

    // ---- stage h_t (16KB): 8 coalesced 8B agent loads -> ds_write_b64 ----
    {
      const u64* src = hb64 + lsrc + (size_t)(t & 1) * 2048;
      u64 v0 = __hip_atomic_load(src + 0 * 32, __ATOMIC_RELAXED, __HIP_MEMORY_SCOPE_AGENT);
      u64 v1 = __hip_atomic_load(src + 1 * 32, __ATOMIC_RELAXED, __HIP_MEMORY_SCOPE_AGENT);
      u64 v2 = __hip_atomic_load(src + 2 * 32, __ATOMIC_RELAXED, __HIP_MEMORY_SCOPE_AGENT);
      u64 v3 = __hip_atomic_load(src + 3 * 32, __ATOMIC_RELAXED, __HIP_MEMORY_SCOPE_AGENT);
      u64 v4 = __hip_atomic_load(src + 4 * 32, __ATOMIC_RELAXED, __HIP_MEMORY_SCOPE_AGENT);
      u64 v5 = __hip_atomic_load(src + 5 * 32, __ATOMIC_RELAXED, __HIP_MEMORY_SCOPE_AGENT);
      u64 v6 = __hip_atomic_load(src + 6 * 32, __ATOMIC_RELAXED, __HIP_MEMORY_SCOPE_AGENT);
      u64 v7 = __hip_atomic_load(src + 7 * 32, __ATOMIC_RELAXED, __HIP_MEMORY_SCOPE_AGENT);
      *(u64*)(ldst + 0 * 128) = v0;
      *(u64*)(ldst + 1 * 128) = v1;
      *(u64*)(ldst + 2 * 128) = v2;
      *(u64*)(ldst + 3 * 128) = v3;
      *(u64*)(ldst + 4 * 128) = v4;
      *(u64*)(ldst + 5 * 128) = v5;
      *(u64*)(ldst + 6 * 128) = v6;
      *(u64*)(ldst + 7 * 128) = v7;
    }
    __syncthreads();

    // ---- MFMA: one 16x16 gate-tile over K=1024 (even/odd chains) ---------
    f4 a0 = {}, a1 = {};
#pragma unroll
    for (int kt = 0; kt < 32; kt++) {
      h8 av = *(const h8*)(hsG + arow * 1032 + (kt << 5) + (q << 3));
      if (kt & 1) a1 = MFMA16(av, B[kt], a1);
      else        a0 = MFMA16(av, B[kt], a0);
    }
    f4 g = a0 + a1;

    // ---- fuse bias+gx, write gate values to xch[cell][gate] (q<2) --------
    if (q < 2) {
#pragma unroll
      for (int r = 0; r < 4; r++) {
        float gh = fxp(g[r] + bh);
        float gv = fxp((float)gxv[r] + gh);
        xchG[((((q << 2) + r) << 4) + cl) * 4 + w] = (_Float16)gv;
      }
    }
    __syncthreads();

    // ---- per-cell gates (waves 2-3), c/h update, publish -----------------
    _Float16* hbw = hbuf + (size_t)G * 16384 + ((t + 1) & 1) * 8192;
    if (isCell) {
      h4 xv = *(const h4*)(xchG + cell * 4);
      float i_ = fxp_rnd(hsig((float)xv[0]));
      float f_ = fxp_rnd(hsig((float)xv[1]));
      float g_ = fxp_rnd(fminf(fmaxf((float)xv[2], -1.0f), 1.0f));
      float o_ = fxp_rnd(hsig((float)xv[3]));
      float cn = fxp(f_ * cG + i_ * g_);
      cG = cn;
      float hn = fxp_rnd(o_ * fminf(fmaxf(cn, -1.0f), 1.0f));
      hG = hn;
      unsigned short hbits = __builtin_bit_cast(unsigned short, (_Float16)hn);
      __hip_atomic_store((unsigned short*)&hbw[row_c * 1024 + jc], hbits,
                         __ATOMIC_RELAXED, __HIP_MEMORY_SCOPE_AGENT);
    }
    __syncthreads();  // drains h stores
    if (tid == 0)
      __hip_atomic_store(myflag, (unsigned)(t + 1), __ATOMIC_RELAXED,
                         __HIP_MEMORY_SCOPE_AGENT);
    // out store after the flag, plain cached (off the sync path)
    if (isCell)
      out[((size_t)((G << 3) + row_c) * 256 + t) * 1024 + jc] = hG;
  };

  for (int t = 0; t < 256; t++) {
    phase(gA, lsA, ldA, hsA, xchA, f2A, flagA, cA, hA, t);
    phase(gB, lsB, ldB, hsB, xchB, f2B, flagB, cB, hB, t);
  }

  if (isCell) {
    out[16777216 + (size_t)((gA << 3) + row_c) * 1024 + jc] = hA;
    out[16777216 + 65536 + (size_t)((gA << 3) + row_c) * 1024 + jc] = cA;
    out[16777216 + (size_t)((gB << 3) + row_c) * 1024 + jc] = hB;
    out[16777216 + 65536 + (size_t)((gB << 3) + row_c) * 1024 + jc] = cB;
  }
}

// ---------------------------------------------------------------------------
extern "C" void kernel_launch(void* const* d_in, const int* in_sizes, int n_in,
                              void* d_out, int out_size, void* d_ws,
                              size_t ws_size, hipStream_t stream) {
  const float* x    = (const float*)d_in[0];
  const float* w_ih = (const float*)d_in[1];
  const float* w_hh = (const float*)d_in[2];
  const float* b_ih = (const float*)d_in[3];
  const float* b_hh = (const float*)d_in[4];
  const float* h0   = (const float*)d_in[5];
  const float* c0   = (const float*)d_in[6];
  float* out = (float*)d_out;

  // workspace layout (bytes); total ~156.3 MB
  char* ws = (char*)d_ws;
  unsigned* flags = (unsigned*)ws;                    // [8][64] u32 = 2 KB
  _Float16* hbuf  = (_Float16*)(ws + 2048);           // 8*2*8*1024*2 = 256 KB
  _Float16* whhq  = (_Float16*)(ws + 264192);         // 8 MB
  _Float16* wihq  = (_Float16*)(ws + 8652800);        // 4 MB
  float*    bihq  = (float*)(ws + 12847104);          // 16 KB
  float*    bhhq  = (float*)(ws + 12863488);          // 16 KB
  _Float16* xq    = (_Float16*)(ws + 12879872);       // 16 MB
  _Float16* gxb   = (_Float16*)(ws + 29657088);       // 128 MB packed

  hipMemsetAsync(flags, 0, 2048, stream);
  qf16_kernel<<<dim3(4096), 256, 0, stream>>>(w_hh, whhq, 4194304 / 4);
  qf16_kernel<<<dim3(2048), 256, 0, stream>>>(w_ih, wihq, 2097152 / 4);
  qx_kernel<<<dim3(8192), 256, 0, stream>>>(x, xq);
  qh0_kernel<<<dim3(64), 256, 0, stream>>>(h0, hbuf);
  qf32_kernel<<<dim3(4), 256, 0, stream>>>(b_ih, bihq, 4096 / 4);
  qf32_kernel<<<dim3(4), 256, 0, stream>>>(b_hh, bhhq, 4096 / 4);
  gemm_gx_kernel<<<dim3(128, 32), 256, 0, stream>>>(xq, wihq, bihq, gxb);
  lstm_kernel<<<dim3(256), 256, 0, stream>>>(whhq, bhhq, gxb, c0, hbuf, out,
                                             flags);
}